// Round 11
// baseline (2241.338 us; speedup 1.0000x reference)
//
#include <hip/hip_runtime.h>
#include <hip/hip_bf16.h>
#include <stdint.h>

#define Bb 128
#define Ss 512
#define Hh 1024
#define Vv 128

#define GROUPS 8
#define WPG 8       // workgroups per group
#define MB 16       // batch rows per group
#define NCOL 128    // output columns per WG

typedef __attribute__((ext_vector_type(8))) short short8;
typedef __attribute__((ext_vector_type(4))) float float4v;
typedef __attribute__((ext_vector_type(4))) unsigned int uint4v;

static __device__ __forceinline__ short f2bf(float f) {
    union { float f; uint32_t u; } x; x.f = f;
    uint32_t r = x.u + 0x7FFFu + ((x.u >> 16) & 1u);   // RNE
    return (short)(r >> 16);
}
static __device__ __forceinline__ float bf2f(uint16_t b) {
    union { uint32_t u; float f; } x; x.u = ((uint32_t)b) << 16;
    return x.f;
}
// fast tanh: 1 - 2/(2^(2x*log2e)+1); approx error ~1e-6 << bf16 rounding
static __device__ __forceinline__ float ftanh(float x) {
    float e = __builtin_amdgcn_exp2f(x * 2.885390082f);
    return 1.0f - 2.0f * __builtin_amdgcn_rcpf(e + 1.0f);
}

// ---------------- Kernel 1: P = emb @ W_ih^T + b_ih + b_hh  ----------------
__global__ void k_prep(const float* __restrict__ emb, const float* __restrict__ Wih,
                       const float* __restrict__ bih, const float* __restrict__ bhh,
                       float* __restrict__ P) {
    int v = blockIdx.x >> 2;                       // 0..127
    int i = ((blockIdx.x & 3) << 8) + threadIdx.x; // 0..1023
    const float4v* e4 = (const float4v*)(emb + v * Hh);
    const float4v* w4 = (const float4v*)(Wih + i * Hh);
    float acc = 0.f;
    #pragma unroll 4
    for (int h = 0; h < Hh / 4; ++h) {
        float4v a = e4[h], b = w4[h];
        acc += a[0]*b[0] + a[1]*b[1] + a[2]*b[2] + a[3]*b[3];
    }
    P[v * Hh + i] = acc + bih[i] + bhh[i];
}

// ---------------- Kernel 2: the 512-step recurrence ----------------
// grid = 64 WGs = 8 groups x 8 WGs (STATIC blockIdx mapping, G16-clean).
// Each WG owns 128 columns (weights in 256 VGPRs/lane). All h traffic
// sc0 sc1 (MALL-coherent). Sync embedded in data: h dword = (bf16<<16)|tag.
// The bulk A-load with per-16B tag-verify IS the poll (detecting attempt
// carries the data); calibrated s_sleep bounds retry traffic.
__launch_bounds__(256, 1)
__global__ void k_rnn(const int* __restrict__ x, const float* __restrict__ Whh,
                      const float* __restrict__ P,
                      uint32_t* __restrict__ h0u, uint32_t* __restrict__ h1u) {
    __shared__ uint8_t x_lds[Ss][MB];        //  8 KB  [t][r], vocab < 256
    __shared__ float   P_lds[Vv][NCOL];      // 64 KB
    __shared__ float4v red[2][4][8][64];     // 64 KB  [pingpong][wave][ntile][lane]

    const int g    = blockIdx.x >> 3;
    const int w    = blockIdx.x & 7;
    const int r0   = g * MB;
    const int n0   = w * NCOL;
    const int tid  = threadIdx.x;
    const int lane = tid & 63;
    const int q    = tid >> 6;            // wave id == K-quarter

    for (int l = tid; l < Ss * MB; l += 256) {
        int t = l >> 4, r = l & 15;
        x_lds[t][r] = (uint8_t)x[(r0 + r) * Ss + t];
    }
    for (int l = tid; l < Vv * NCOL; l += 256) {
        int v = l >> 7, c = l & 127;
        P_lds[v][c] = P[v * Hh + n0 + c];
    }

    // W_hh slice -> bf16 MFMA B-fragments (8 n-tiles x 8 k-slices = 256 VGPRs).
    // B[k][n] = W_hh[n0 + nt*16 + (lane&15)][k], k = q*256 + s*32 + (lane>>4)*8 + e
    short8 bf[8][8];
    {
        const int n_lane = lane & 15;
        const int k_base = q * 256 + ((lane >> 4) << 3);
        #pragma unroll
        for (int nt = 0; nt < 8; ++nt) {
            const float* wrow = Whh + (size_t)(n0 + nt * 16 + n_lane) * Hh;
            #pragma unroll
            for (int s = 0; s < 8; ++s) {
                const float* src = wrow + k_base + s * 32;
                short8 tmp;
                #pragma unroll
                for (int e = 0; e < 8; ++e) tmp[e] = f2bf(src[e]);
                bf[nt][s] = tmp;
            }
        }
    }
    __syncthreads();

    const int row_base = (lane >> 4) << 2;    // D row = (lane>>4)*4 + e
    const int c_lane   = lane & 15;           // D col = lane&15 ; A row = lane&15
    int budget = 1 << 22;                     // absolute anti-hang cap

    for (int t = 0; t < Ss; ++t) {
        float4v acc0 = {0.f,0.f,0.f,0.f}, acc1 = {0.f,0.f,0.f,0.f};
        float4v acc2 = {0.f,0.f,0.f,0.f}, acc3 = {0.f,0.f,0.f,0.f};
        float4v acc4 = {0.f,0.f,0.f,0.f}, acc5 = {0.f,0.f,0.f,0.f};
        float4v acc6 = {0.f,0.f,0.f,0.f}, acc7 = {0.f,0.f,0.f,0.f};

        if (t > 0) {
            const uint32_t tag = (uint32_t)t;
            const uint32_t* hin = (t & 1) ? h1u : h0u;
            // A[m][k]: m = c_lane, k = q*256 + s*32 + (lane>>4)*8 + e
            const uint32_t* arow = hin + (size_t)(r0 + c_lane) * Hh + q * 256
                                   + ((lane >> 4) << 3);
            uint4v dd[16];
            __builtin_amdgcn_s_sleep(16);   // ~1024cy: cover store->visible lag
            for (;;) {
                asm volatile(
                    "global_load_dwordx4 %0, %8, off sc0 sc1\n\t"
                    "global_load_dwordx4 %1, %8, off offset:16 sc0 sc1\n\t"
                    "global_load_dwordx4 %2, %8, off offset:128 sc0 sc1\n\t"
                    "global_load_dwordx4 %3, %8, off offset:144 sc0 sc1\n\t"
                    "global_load_dwordx4 %4, %8, off offset:256 sc0 sc1\n\t"
                    "global_load_dwordx4 %5, %8, off offset:272 sc0 sc1\n\t"
                    "global_load_dwordx4 %6, %8, off offset:384 sc0 sc1\n\t"
                    "global_load_dwordx4 %7, %8, off offset:400 sc0 sc1"
                    : "=&v"(dd[0]), "=&v"(dd[1]), "=&v"(dd[2]), "=&v"(dd[3]),
                      "=&v"(dd[4]), "=&v"(dd[5]), "=&v"(dd[6]), "=&v"(dd[7])
                    : "v"(arow) : "memory");
                asm volatile(
                    "global_load_dwordx4 %0, %8, off offset:512 sc0 sc1\n\t"
                    "global_load_dwordx4 %1, %8, off offset:528 sc0 sc1\n\t"
                    "global_load_dwordx4 %2, %8, off offset:640 sc0 sc1\n\t"
                    "global_load_dwordx4 %3, %8, off offset:656 sc0 sc1\n\t"
                    "global_load_dwordx4 %4, %8, off offset:768 sc0 sc1\n\t"
                    "global_load_dwordx4 %5, %8, off offset:784 sc0 sc1\n\t"
                    "global_load_dwordx4 %6, %8, off offset:896 sc0 sc1\n\t"
                    "global_load_dwordx4 %7, %8, off offset:912 sc0 sc1\n\t"
                    "s_waitcnt vmcnt(0)"
                    : "=&v"(dd[8]), "=&v"(dd[9]), "=&v"(dd[10]), "=&v"(dd[11]),
                      "=&v"(dd[12]), "=&v"(dd[13]), "=&v"(dd[14]), "=&v"(dd[15])
                    : "v"(arow) : "memory");
                // one tag per 16B chunk: chunk lies in one 32B sector written
                // by a single producer store instruction (sector-atomic).
                uint32_t ok = 1u;
                #pragma unroll
                for (int i = 0; i < 16; ++i) ok &= (uint32_t)((dd[i].x & 0xFFFFu) == tag);
                if (__all((int)ok)) break;
                if (--budget <= 0) break;
                __builtin_amdgcn_s_sleep(4);   // throttle retries (~256cy)
            }

            // extract bf16 pairs, run 8 n-tiles x 8 k-slices of MFMA
            #define PK(d0, d1) (((d0) >> 16) | ((d1) & 0xFFFF0000u))
            #pragma unroll
            for (int s = 0; s < 8; ++s) {
                uint4v lo = dd[2 * s], hi = dd[2 * s + 1];
                uint4v pk = { PK(lo.x, lo.y), PK(lo.z, lo.w),
                              PK(hi.x, hi.y), PK(hi.z, hi.w) };
                short8 a;
                __builtin_memcpy(&a, &pk, 16);
                acc0 = __builtin_amdgcn_mfma_f32_16x16x32_bf16(a, bf[0][s], acc0, 0,0,0);
                acc1 = __builtin_amdgcn_mfma_f32_16x16x32_bf16(a, bf[1][s], acc1, 0,0,0);
                acc2 = __builtin_amdgcn_mfma_f32_16x16x32_bf16(a, bf[2][s], acc2, 0,0,0);
                acc3 = __builtin_amdgcn_mfma_f32_16x16x32_bf16(a, bf[3][s], acc3, 0,0,0);
                acc4 = __builtin_amdgcn_mfma_f32_16x16x32_bf16(a, bf[4][s], acc4, 0,0,0);
                acc5 = __builtin_amdgcn_mfma_f32_16x16x32_bf16(a, bf[5][s], acc5, 0,0,0);
                acc6 = __builtin_amdgcn_mfma_f32_16x16x32_bf16(a, bf[6][s], acc6, 0,0,0);
                acc7 = __builtin_amdgcn_mfma_f32_16x16x32_bf16(a, bf[7][s], acc7, 0,0,0);
            }
            #undef PK
        }

        const int pb = t & 1;
        red[pb][q][0][lane] = acc0;
        red[pb][q][1][lane] = acc1;
        red[pb][q][2][lane] = acc2;
        red[pb][q][3][lane] = acc3;
        red[pb][q][4][lane] = acc4;
        red[pb][q][5][lane] = acc5;
        red[pb][q][6][lane] = acc6;
        red[pb][q][7][lane] = acc7;
        __syncthreads();   // the ONLY barrier per step (red ping-pongs)

        // wave q: reduce n-tiles 2q, 2q+1; add P, tanh, store tagged dwords
        {
            uint32_t* hout = ((t + 1) & 1) ? h1u : h0u;
            const uint32_t t1 = (uint32_t)(t + 1);
            int v0i = x_lds[t][row_base + 0], v1i = x_lds[t][row_base + 1];
            int v2i = x_lds[t][row_base + 2], v3i = x_lds[t][row_base + 3];
            #pragma unroll
            for (int j = 0; j < 2; ++j) {
                const int nt = (q << 1) + j;
                float4v u = red[pb][0][nt][lane];
                u += red[pb][1][nt][lane];
                u += red[pb][2][nt][lane];
                u += red[pb][3][nt][lane];
                const int pcol = (nt << 4) + c_lane;
                const int ncol = n0 + pcol;
                uint32_t b0 = ((uint32_t)(uint16_t)f2bf(ftanh(u[0] + P_lds[v0i][pcol])) << 16) | t1;
                uint32_t b1 = ((uint32_t)(uint16_t)f2bf(ftanh(u[1] + P_lds[v1i][pcol])) << 16) | t1;
                uint32_t b2 = ((uint32_t)(uint16_t)f2bf(ftanh(u[2] + P_lds[v2i][pcol])) << 16) | t1;
                uint32_t b3 = ((uint32_t)(uint16_t)f2bf(ftanh(u[3] + P_lds[v3i][pcol])) << 16) | t1;
                uint32_t* p0 = hout + (size_t)(r0 + row_base) * Hh + ncol;
                asm volatile("global_store_dword %0, %1, off sc0 sc1"
                             :: "v"(p0),          "v"(b0) : "memory");
                asm volatile("global_store_dword %0, %1, off sc0 sc1"
                             :: "v"(p0 + Hh),     "v"(b1) : "memory");
                asm volatile("global_store_dword %0, %1, off sc0 sc1"
                             :: "v"(p0 + 2 * Hh), "v"(b2) : "memory");
                asm volatile("global_store_dword %0, %1, off sc0 sc1"
                             :: "v"(p0 + 3 * Hh), "v"(b3) : "memory");
            }
        }
    }
}

// ---------------- Kernel 3: out = hT @ W_fc^T + b_fc ----------------
// hT is the tagged-u32 h buffer; value = dword >> 16.
__global__ void k_fc(const uint32_t* __restrict__ hT, const float* __restrict__ Wfc,
                     const float* __restrict__ bfc, float* __restrict__ out) {
    int bb = (blockIdx.x >> 3) << 4;
    int vb = (blockIdx.x & 7) << 4;
    int b  = bb + (threadIdx.x >> 4);
    int v  = vb + (threadIdx.x & 15);
    const uint32_t* hrow = hT + (size_t)b * Hh;
    const float*    wrow = Wfc + (size_t)v * Hh;
    float acc = 0.f;
    #pragma unroll 4
    for (int i = 0; i < Hh; i += 4) {
        float4v wv = *(const float4v*)(wrow + i);
        acc += bf2f((uint16_t)(hrow[i + 0] >> 16)) * wv[0]
             + bf2f((uint16_t)(hrow[i + 1] >> 16)) * wv[1]
             + bf2f((uint16_t)(hrow[i + 2] >> 16)) * wv[2]
             + bf2f((uint16_t)(hrow[i + 3] >> 16)) * wv[3];
    }
    out[(size_t)b * Vv + v] = acc + bfc[v];
}

extern "C" void kernel_launch(void* const* d_in, const int* in_sizes, int n_in,
                              void* d_out, int out_size, void* d_ws, size_t ws_size,
                              hipStream_t stream) {
    const int*   x   = (const int*)d_in[0];
    const float* emb = (const float*)d_in[1];
    const float* Wih = (const float*)d_in[2];
    const float* Whh = (const float*)d_in[3];
    const float* bih = (const float*)d_in[4];
    const float* bhh = (const float*)d_in[5];
    const float* Wfc = (const float*)d_in[6];
    const float* bfc = (const float*)d_in[7];
    float* out = (float*)d_out;

    char* ws = (char*)d_ws;
    float*    P   = (float*)ws;                        // 512 KB: [128][1024] f32
    uint32_t* h0u = (uint32_t*)(ws + (512 << 10));     // 512 KB: tagged dwords
    uint32_t* h1u = (uint32_t*)(ws + (1024 << 10));    // 512 KB
    // No sync state, no memset: tags self-validate (poison 0xAAAA is never a
    // valid step tag; stale same-tag data across graph replays is byte-identical
    // by determinism, hence harmless).

    k_prep<<<512, 256, 0, stream>>>(emb, Wih, bih, bhh, P);
    k_rnn<<<64, 256, 0, stream>>>(x, Whh, P, h0u, h1u);
    // final h (t=512, even) lives in h0u
    k_fc<<<64, 256, 0, stream>>>(h0u, Wfc, bfc, out);
}

// Round 12
// 2085.035 us; speedup vs baseline: 1.0750x; 1.0750x over previous
//
#include <hip/hip_runtime.h>
#include <hip/hip_bf16.h>
#include <stdint.h>

#define Bb 128
#define Ss 512
#define Hh 1024
#define Vv 128

#define GROUPS 8
#define WPG 16      // workgroups per group
#define MB 16       // batch rows per group
#define NCOL 64     // output columns per WG

typedef __attribute__((ext_vector_type(8))) short short8;
typedef __attribute__((ext_vector_type(4))) float float4v;
typedef __attribute__((ext_vector_type(4))) unsigned int uint4v;

static __device__ __forceinline__ short f2bf(float f) {
    union { float f; uint32_t u; } x; x.f = f;
    uint32_t r = x.u + 0x7FFFu + ((x.u >> 16) & 1u);   // RNE
    return (short)(r >> 16);
}
static __device__ __forceinline__ float bf2f(uint16_t b) {
    union { uint32_t u; float f; } x; x.u = ((uint32_t)b) << 16;
    return x.f;
}
// fast tanh: 1 - 2/(2^(2x*log2e)+1); approx error ~1e-6 << bf16 rounding
static __device__ __forceinline__ float ftanh(float x) {
    float e = __builtin_amdgcn_exp2f(x * 2.885390082f);
    return 1.0f - 2.0f * __builtin_amdgcn_rcpf(e + 1.0f);
}

// ---------------- Kernel 1: P = emb @ W_ih^T + b_ih + b_hh  ----------------
__global__ void k_prep(const float* __restrict__ emb, const float* __restrict__ Wih,
                       const float* __restrict__ bih, const float* __restrict__ bhh,
                       float* __restrict__ P) {
    int v = blockIdx.x >> 2;                       // 0..127
    int i = ((blockIdx.x & 3) << 8) + threadIdx.x; // 0..1023
    const float4v* e4 = (const float4v*)(emb + v * Hh);
    const float4v* w4 = (const float4v*)(Wih + i * Hh);
    float acc = 0.f;
    #pragma unroll 4
    for (int h = 0; h < Hh / 4; ++h) {
        float4v a = e4[h], b = w4[h];
        acc += a[0]*b[0] + a[1]*b[1] + a[2]*b[2] + a[3]*b[3];
    }
    P[v * Hh + i] = acc + bih[i] + bhh[i];
}

// ---------------- Kernel 2: the 512-step recurrence ----------------
// grid = 128 WGs = 8 groups x 16 WGs (STATIC blockIdx mapping, G16-clean).
// All h traffic sc0 sc1 (MALL-coherent, zero cache maintenance). Sync is
// embedded in the data: h dword = (bf16 value << 16) | step_tag. The bulk
// A-load with per-16B tag-verify IS the poll - no probe phase, no flags,
// no store-ack. Stale tags -> s_sleep(1) backoff + retry (rare, bounded).
__launch_bounds__(256, 1)
__global__ void k_rnn(const int* __restrict__ x, const float* __restrict__ Whh,
                      const float* __restrict__ P,
                      uint32_t* __restrict__ h0u, uint32_t* __restrict__ h1u) {
    __shared__ int     x_lds[Ss][MB];        // 32 KB  [t][r]
    __shared__ float   P_lds[Vv][NCOL];      // 32 KB
    __shared__ float4v red[2][4][4][64];     // 32 KB  [pingpong][wave][ntile][lane]

    const int g    = blockIdx.x >> 4;
    const int w    = blockIdx.x & 15;
    const int r0   = g * MB;
    const int n0   = w * NCOL;
    const int tid  = threadIdx.x;
    const int lane = tid & 63;
    const int q    = tid >> 6;            // wave id == K-quarter

    for (int l = tid; l < Ss * MB; l += 256) {
        int t = l >> 4, r = l & 15;
        x_lds[t][r] = x[(r0 + r) * Ss + t];
    }
    for (int l = tid; l < Vv * NCOL; l += 256) {
        int v = l >> 6, c = l & 63;
        P_lds[v][c] = P[v * Hh + n0 + c];
    }

    // W_hh slice -> bf16 MFMA B-fragments (128 VGPRs).
    // B[k][n] = W_hh[n0 + nt*16 + (lane&15)][k], k = q*256 + s*32 + (lane>>4)*8 + e
    short8 bf[4][8];
    {
        const int n_lane = lane & 15;
        const int k_base = q * 256 + ((lane >> 4) << 3);
        #pragma unroll
        for (int nt = 0; nt < 4; ++nt) {
            const float* wrow = Whh + (size_t)(n0 + nt * 16 + n_lane) * Hh;
            #pragma unroll
            for (int s = 0; s < 8; ++s) {
                const float* src = wrow + k_base + s * 32;
                short8 tmp;
                #pragma unroll
                for (int e = 0; e < 8; ++e) tmp[e] = f2bf(src[e]);
                bf[nt][s] = tmp;
            }
        }
    }
    __syncthreads();

    const int row_base = (lane >> 4) << 2;    // D row = (lane>>4)*4 + e
    const int c_lane   = lane & 15;           // D col = lane&15 ; A row = lane&15
    int budget = 1 << 18;                     // anti-hang cap (fail fast, visibly)

    for (int t = 0; t < Ss; ++t) {
        float4v acc0 = {0.f,0.f,0.f,0.f}, acc1 = {0.f,0.f,0.f,0.f};
        float4v acc2 = {0.f,0.f,0.f,0.f}, acc3 = {0.f,0.f,0.f,0.f};

        if (t > 0) {
            const uint32_t tag = (uint32_t)t;
            const uint32_t* hin = (t & 1) ? h1u : h0u;
            // A[m][k]: m = c_lane, k = q*256 + s*32 + (lane>>4)*8 + e
            const uint32_t* arow = hin + (size_t)(r0 + c_lane) * Hh + q * 256
                                   + ((lane >> 4) << 3);
            uint4v dd[16];
            for (;;) {
                asm volatile(
                    "global_load_dwordx4 %0, %8, off sc0 sc1\n\t"
                    "global_load_dwordx4 %1, %8, off offset:16 sc0 sc1\n\t"
                    "global_load_dwordx4 %2, %8, off offset:128 sc0 sc1\n\t"
                    "global_load_dwordx4 %3, %8, off offset:144 sc0 sc1\n\t"
                    "global_load_dwordx4 %4, %8, off offset:256 sc0 sc1\n\t"
                    "global_load_dwordx4 %5, %8, off offset:272 sc0 sc1\n\t"
                    "global_load_dwordx4 %6, %8, off offset:384 sc0 sc1\n\t"
                    "global_load_dwordx4 %7, %8, off offset:400 sc0 sc1"
                    : "=&v"(dd[0]), "=&v"(dd[1]), "=&v"(dd[2]), "=&v"(dd[3]),
                      "=&v"(dd[4]), "=&v"(dd[5]), "=&v"(dd[6]), "=&v"(dd[7])
                    : "v"(arow) : "memory");
                asm volatile(
                    "global_load_dwordx4 %0, %8, off offset:512 sc0 sc1\n\t"
                    "global_load_dwordx4 %1, %8, off offset:528 sc0 sc1\n\t"
                    "global_load_dwordx4 %2, %8, off offset:640 sc0 sc1\n\t"
                    "global_load_dwordx4 %3, %8, off offset:656 sc0 sc1\n\t"
                    "global_load_dwordx4 %4, %8, off offset:768 sc0 sc1\n\t"
                    "global_load_dwordx4 %5, %8, off offset:784 sc0 sc1\n\t"
                    "global_load_dwordx4 %6, %8, off offset:896 sc0 sc1\n\t"
                    "global_load_dwordx4 %7, %8, off offset:912 sc0 sc1\n\t"
                    "s_waitcnt vmcnt(0)"
                    : "=&v"(dd[8]), "=&v"(dd[9]), "=&v"(dd[10]), "=&v"(dd[11]),
                      "=&v"(dd[12]), "=&v"(dd[13]), "=&v"(dd[14]), "=&v"(dd[15])
                    : "v"(arow) : "memory");
                // one tag per 16B chunk: chunk lies in one 32B sector written
                // by a single producer store instruction (sector-atomic).
                uint32_t ok = 1u;
                #pragma unroll
                for (int i = 0; i < 16; ++i) ok &= (uint32_t)((dd[i].x & 0xFFFFu) == tag);
                if (__all((int)ok)) break;
                if (--budget <= 0) break;
                __builtin_amdgcn_s_sleep(1);   // ~64cy backoff: bounds retry traffic
            }

            // extract bf16 pairs and run MFMA
            #define PK(d0, d1) (((d0) >> 16) | ((d1) & 0xFFFF0000u))
            #pragma unroll
            for (int s = 0; s < 8; ++s) {
                uint4v lo = dd[2 * s], hi = dd[2 * s + 1];
                uint4v pk = { PK(lo.x, lo.y), PK(lo.z, lo.w),
                              PK(hi.x, hi.y), PK(hi.z, hi.w) };
                short8 a;
                __builtin_memcpy(&a, &pk, 16);
                acc0 = __builtin_amdgcn_mfma_f32_16x16x32_bf16(a, bf[0][s], acc0, 0,0,0);
                acc1 = __builtin_amdgcn_mfma_f32_16x16x32_bf16(a, bf[1][s], acc1, 0,0,0);
                acc2 = __builtin_amdgcn_mfma_f32_16x16x32_bf16(a, bf[2][s], acc2, 0,0,0);
                acc3 = __builtin_amdgcn_mfma_f32_16x16x32_bf16(a, bf[3][s], acc3, 0,0,0);
            }
            #undef PK
        }

        const int pb = t & 1;
        red[pb][q][0][lane] = acc0;
        red[pb][q][1][lane] = acc1;
        red[pb][q][2][lane] = acc2;
        red[pb][q][3][lane] = acc3;
        __syncthreads();   // the ONLY barrier per step (red ping-pongs)

        // wave q: reduce n-tile q, add P, tanh, store tagged dwords
        {
            float4v u = red[pb][0][q][lane];
            u += red[pb][1][q][lane];
            u += red[pb][2][q][lane];
            u += red[pb][3][q][lane];
            uint32_t* hout = ((t + 1) & 1) ? h1u : h0u;
            const int pcol = q * 16 + c_lane;
            const int ncol = n0 + pcol;
            int v0i = x_lds[t][row_base + 0], v1i = x_lds[t][row_base + 1];
            int v2i = x_lds[t][row_base + 2], v3i = x_lds[t][row_base + 3];
            const uint32_t t1 = (uint32_t)(t + 1);
            uint32_t b0 = ((uint32_t)(uint16_t)f2bf(ftanh(u[0] + P_lds[v0i][pcol])) << 16) | t1;
            uint32_t b1 = ((uint32_t)(uint16_t)f2bf(ftanh(u[1] + P_lds[v1i][pcol])) << 16) | t1;
            uint32_t b2 = ((uint32_t)(uint16_t)f2bf(ftanh(u[2] + P_lds[v2i][pcol])) << 16) | t1;
            uint32_t b3 = ((uint32_t)(uint16_t)f2bf(ftanh(u[3] + P_lds[v3i][pcol])) << 16) | t1;
            uint32_t* p0 = hout + (size_t)(r0 + row_base) * Hh + ncol;
            // 4 fire-and-forget full-line stores; no ack, no flag.
            asm volatile("global_store_dword %0, %1, off sc0 sc1"
                         :: "v"(p0),            "v"(b0) : "memory");
            asm volatile("global_store_dword %0, %1, off sc0 sc1"
                         :: "v"(p0 + Hh),       "v"(b1) : "memory");
            asm volatile("global_store_dword %0, %1, off sc0 sc1"
                         :: "v"(p0 + 2 * Hh),   "v"(b2) : "memory");
            asm volatile("global_store_dword %0, %1, off sc0 sc1"
                         :: "v"(p0 + 3 * Hh),   "v"(b3) : "memory");
        }
    }
}

// ---------------- Kernel 3: out = hT @ W_fc^T + b_fc ----------------
// hT is the tagged-u32 h buffer; value = dword >> 16.
__global__ void k_fc(const uint32_t* __restrict__ hT, const float* __restrict__ Wfc,
                     const float* __restrict__ bfc, float* __restrict__ out) {
    int bb = (blockIdx.x >> 3) << 4;
    int vb = (blockIdx.x & 7) << 4;
    int b  = bb + (threadIdx.x >> 4);
    int v  = vb + (threadIdx.x & 15);
    const uint32_t* hrow = hT + (size_t)b * Hh;
    const float*    wrow = Wfc + (size_t)v * Hh;
    float acc = 0.f;
    #pragma unroll 4
    for (int i = 0; i < Hh; i += 4) {
        float4v wv = *(const float4v*)(wrow + i);
        acc += bf2f((uint16_t)(hrow[i + 0] >> 16)) * wv[0]
             + bf2f((uint16_t)(hrow[i + 1] >> 16)) * wv[1]
             + bf2f((uint16_t)(hrow[i + 2] >> 16)) * wv[2]
             + bf2f((uint16_t)(hrow[i + 3] >> 16)) * wv[3];
    }
    out[(size_t)b * Vv + v] = acc + bfc[v];
}

extern "C" void kernel_launch(void* const* d_in, const int* in_sizes, int n_in,
                              void* d_out, int out_size, void* d_ws, size_t ws_size,
                              hipStream_t stream) {
    const int*   x   = (const int*)d_in[0];
    const float* emb = (const float*)d_in[1];
    const float* Wih = (const float*)d_in[2];
    const float* Whh = (const float*)d_in[3];
    const float* bih = (const float*)d_in[4];
    const float* bhh = (const float*)d_in[5];
    const float* Wfc = (const float*)d_in[6];
    const float* bfc = (const float*)d_in[7];
    float* out = (float*)d_out;

    char* ws = (char*)d_ws;
    float*    P   = (float*)ws;                        // 512 KB: [128][1024] f32
    uint32_t* h0u = (uint32_t*)(ws + (512 << 10));     // 512 KB: tagged dwords
    uint32_t* h1u = (uint32_t*)(ws + (1024 << 10));    // 512 KB
    // No sync state, no memset: tags self-validate (poison 0xAAAA is never a
    // valid step tag; stale same-tag data across graph replays is byte-identical
    // by determinism, hence harmless).

    k_prep<<<512, 256, 0, stream>>>(emb, Wih, bih, bhh, P);
    k_rnn<<<128, 256, 0, stream>>>(x, Whh, P, h0u, h1u);
    // final h (t=512, even) lives in h0u
    k_fc<<<64, 256, 0, stream>>>(h0u, Wfc, bfc, out);
}

// Round 13
// 1798.496 us; speedup vs baseline: 1.2462x; 1.1593x over previous
//
#include <hip/hip_runtime.h>
#include <hip/hip_bf16.h>
#include <stdint.h>

#define Bb 128
#define Ss 512
#define Hh 1024
#define Vv 128

#define GROUPS 8
#define WPG 16      // workgroups per group
#define MB 16       // batch rows per group
#define NCOL 64     // output columns per WG

typedef __attribute__((ext_vector_type(8))) short short8;
typedef __attribute__((ext_vector_type(4))) float float4v;

static __device__ __forceinline__ short f2bf(float f) {
    union { float f; uint32_t u; } x; x.f = f;
    uint32_t r = x.u + 0x7FFFu + ((x.u >> 16) & 1u);   // RNE
    return (short)(r >> 16);
}
static __device__ __forceinline__ float bf2f(uint16_t b) {
    union { uint32_t u; float f; } x; x.u = ((uint32_t)b) << 16;
    return x.f;
}

// ---------------- Kernel 1: P = emb @ W_ih^T + b_ih + b_hh  ----------------
__global__ void k_prep(const float* __restrict__ emb, const float* __restrict__ Wih,
                       const float* __restrict__ bih, const float* __restrict__ bhh,
                       float* __restrict__ P) {
    int v = blockIdx.x >> 2;                       // 0..127
    int i = ((blockIdx.x & 3) << 8) + threadIdx.x; // 0..1023
    const float4v* e4 = (const float4v*)(emb + v * Hh);
    const float4v* w4 = (const float4v*)(Wih + i * Hh);
    float acc = 0.f;
    #pragma unroll 4
    for (int h = 0; h < Hh / 4; ++h) {
        float4v a = e4[h], b = w4[h];
        acc += a[0]*b[0] + a[1]*b[1] + a[2]*b[2] + a[3]*b[3];
    }
    P[v * Hh + i] = acc + bih[i] + bhh[i];
}

// ---------------- Kernel 2: the 512-step recurrence ----------------
// grid = 128 WGs = 8 groups x 16 WGs, block = 256 threads (4 waves).
// All h/flag traffic: sc0 sc1 (MALL-coherent, zero cache-maintenance ops).
// Sync: ONE flag per WG (16B-padded), stored by wave 0 after a single
// vmcnt(0) ack of its full-line h stores; wave 1 polls (overlaps wave 0's
// store+ack+flag with poll startup).
__launch_bounds__(256, 1)
__global__ void k_rnn(const int* __restrict__ x, const float* __restrict__ Whh,
                      const float* __restrict__ P,
                      uint16_t* __restrict__ h0, uint16_t* __restrict__ h1,
                      uint32_t* __restrict__ flags) {
    __shared__ int      x_lds[Ss][MB];      // 32 KB  [t][r]
    __shared__ float    P_lds[Vv][NCOL];    // 32 KB
    __shared__ float4v  red[4][4][64];      // 16 KB  [wave][ntile][lane]
    __shared__ uint16_t out_t[MB][NCOL];    //  2 KB  row-major result tile

    const int g    = blockIdx.x >> 4;
    const int w    = blockIdx.x & 15;
    const int r0   = g * MB;
    const int n0   = w * NCOL;
    const int tid  = threadIdx.x;
    const int lane = tid & 63;
    const int q    = tid >> 6;            // wave id == K-quarter

    // stage x slice: x_lds[t][r] = x[(r0+r)*S + t]
    for (int l = tid; l < Ss * MB; l += 256) {
        int t = l >> 4, r = l & 15;
        x_lds[t][r] = x[(r0 + r) * Ss + t];
    }
    // stage P slice (columns n0..n0+63, all 128 vocab rows)
    for (int l = tid; l < Vv * NCOL; l += 256) {
        int v = l >> 6, c = l & 63;
        P_lds[v][c] = P[v * Hh + n0 + c];
    }

    // W_hh slice -> registers as bf16 MFMA B-fragments (128 VGPRs).
    // B[k][n] = W_hh[n0 + nt*16 + (lane&15)][k],  k = q*256 + s*32 + (lane>>4)*8 + e
    short8 bf[4][8];
    {
        const int n_lane = lane & 15;
        const int k_base = q * 256 + ((lane >> 4) << 3);
        #pragma unroll
        for (int nt = 0; nt < 4; ++nt) {
            const float* wrow = Whh + (size_t)(n0 + nt * 16 + n_lane) * Hh;
            #pragma unroll
            for (int s = 0; s < 8; ++s) {
                const float* src = wrow + k_base + s * 32;
                short8 tmp;
                #pragma unroll
                for (int e = 0; e < 8; ++e) tmp[e] = f2bf(src[e]);
                bf[nt][s] = tmp;
            }
        }
    }
    __syncthreads();

    // flag layout: one u32 per WG, padded to 16B -> one group = 16 x 16B = 4 lines.
    uint32_t*       myflag = flags + (((g << 4) + w) << 2);
    const uint32_t* pollp  = flags + (((g << 4) + (lane & 15)) << 2);

    const int row_base = (lane >> 4) << 2;    // D row = (lane>>4)*4 + e
    const int c_lane   = lane & 15;           // D col = lane&15 ; A row = lane&15
    int budget = 1 << 24;                     // anti-hang cap

    for (int t = 0; t < Ss; ++t) {
        float4v acc0 = {0.f,0.f,0.f,0.f}, acc1 = {0.f,0.f,0.f,0.f};
        float4v acc2 = {0.f,0.f,0.f,0.f}, acc3 = {0.f,0.f,0.f,0.f};

        if (t > 0) {
            // ---- group barrier: wave 1 polls the 16 WG-flags, others park.
            // (wave 0 is still finishing store+ack+flag of step t-1 -> overlap)
            if (q == 1) {
                const uint32_t tgt = (uint32_t)t;
                uint32_t fv;
                do {
                    asm volatile("global_load_dword %0, %1, off sc0 sc1\n\t"
                                 "s_waitcnt vmcnt(0)"
                                 : "=v"(fv) : "v"(pollp) : "memory");
                    if (--budget <= 0) break;
                } while (!__all((int)(fv >= tgt)));
            }
            __syncthreads();   // #1: release — h_t is visible at MALL

            const uint16_t* hin = (t & 1) ? h1 : h0;
            // A[m][k]: m = lane&15 (batch row), k = q*256 + s*32 + (lane>>4)*8 + e
            const uint16_t* arow = hin + (size_t)(r0 + c_lane) * Hh + q * 256 + ((lane >> 4) << 3);
            short8 a0,a1,a2,a3,a4,a5,a6,a7;
            asm volatile(
                "global_load_dwordx4 %0, %8, off sc0 sc1\n\t"
                "global_load_dwordx4 %1, %8, off offset:64 sc0 sc1\n\t"
                "global_load_dwordx4 %2, %8, off offset:128 sc0 sc1\n\t"
                "global_load_dwordx4 %3, %8, off offset:192 sc0 sc1\n\t"
                "global_load_dwordx4 %4, %8, off offset:256 sc0 sc1\n\t"
                "global_load_dwordx4 %5, %8, off offset:320 sc0 sc1\n\t"
                "global_load_dwordx4 %6, %8, off offset:384 sc0 sc1\n\t"
                "global_load_dwordx4 %7, %8, off offset:448 sc0 sc1\n\t"
                "s_waitcnt vmcnt(0)"
                : "=&v"(a0), "=&v"(a1), "=&v"(a2), "=&v"(a3),
                  "=&v"(a4), "=&v"(a5), "=&v"(a6), "=&v"(a7)
                : "v"(arow)
                : "memory");
            #define MM(s, areg) \
                acc0 = __builtin_amdgcn_mfma_f32_16x16x32_bf16(areg, bf[0][s], acc0, 0,0,0); \
                acc1 = __builtin_amdgcn_mfma_f32_16x16x32_bf16(areg, bf[1][s], acc1, 0,0,0); \
                acc2 = __builtin_amdgcn_mfma_f32_16x16x32_bf16(areg, bf[2][s], acc2, 0,0,0); \
                acc3 = __builtin_amdgcn_mfma_f32_16x16x32_bf16(areg, bf[3][s], acc3, 0,0,0);
            MM(0,a0) MM(1,a1) MM(2,a2) MM(3,a3) MM(4,a4) MM(5,a5) MM(6,a6) MM(7,a7)
            #undef MM
        }

        red[q][0][lane] = acc0;
        red[q][1][lane] = acc1;
        red[q][2][lane] = acc2;
        red[q][3][lane] = acc3;
        __syncthreads();   // #2

        // wave q reduces its n-tile, tanh, write bf16 into LDS tile
        {
            float4v u = red[0][q][lane];
            u += red[1][q][lane];
            u += red[2][q][lane];
            u += red[3][q][lane];
            const int pcol = q * 16 + c_lane;
            int v0i = x_lds[t][row_base + 0], v1i = x_lds[t][row_base + 1];
            int v2i = x_lds[t][row_base + 2], v3i = x_lds[t][row_base + 3];
            out_t[row_base + 0][pcol] = (uint16_t)f2bf(tanhf(u[0] + P_lds[v0i][pcol]));
            out_t[row_base + 1][pcol] = (uint16_t)f2bf(tanhf(u[1] + P_lds[v1i][pcol]));
            out_t[row_base + 2][pcol] = (uint16_t)f2bf(tanhf(u[2] + P_lds[v2i][pcol]));
            out_t[row_base + 3][pcol] = (uint16_t)f2bf(tanhf(u[3] + P_lds[v3i][pcol]));
        }
        __syncthreads();   // #3: out_t complete

        // wave 0: full-line coalesced store of the 16x64 tile + ack + flag
        if (q == 0) {
            uint16_t* hout = ((t + 1) & 1) ? h1 : h0;
            const uint32_t* o32 = (const uint32_t*)out_t;   // [16][32]
            const int rhalf = (lane >> 5) << 3;             // 0 or 8
            const int c32   = lane & 31;
            uint32_t sv[8];
            const uint32_t* sp[8];
            #pragma unroll
            for (int k = 0; k < 8; ++k) {
                int row = rhalf + k;
                sv[k] = o32[row * 32 + c32];
                sp[k] = (const uint32_t*)(hout + (size_t)(r0 + row) * Hh + n0 + (c32 << 1));
            }
            const uint32_t tp1 = (uint32_t)(t + 1);
            asm volatile(
                "global_store_dword %8, %0, off sc0 sc1\n\t"
                "global_store_dword %9, %1, off sc0 sc1\n\t"
                "global_store_dword %10, %2, off sc0 sc1\n\t"
                "global_store_dword %11, %3, off sc0 sc1\n\t"
                "global_store_dword %12, %4, off sc0 sc1\n\t"
                "global_store_dword %13, %5, off sc0 sc1\n\t"
                "global_store_dword %14, %6, off sc0 sc1\n\t"
                "global_store_dword %15, %7, off sc0 sc1\n\t"
                "s_waitcnt vmcnt(0)\n\t"
                "global_store_dword %16, %17, off sc0 sc1"
                :: "v"(sv[0]), "v"(sv[1]), "v"(sv[2]), "v"(sv[3]),
                   "v"(sv[4]), "v"(sv[5]), "v"(sv[6]), "v"(sv[7]),
                   "v"(sp[0]), "v"(sp[1]), "v"(sp[2]), "v"(sp[3]),
                   "v"(sp[4]), "v"(sp[5]), "v"(sp[6]), "v"(sp[7]),
                   "v"(myflag), "v"(tp1)
                : "memory");
        }
    }
}

// ---------------- Kernel 3: out = hT @ W_fc^T + b_fc ----------------
// grid 64 (8x8 tiles of 16x16), block 256, one output per thread
__global__ void k_fc(const uint16_t* __restrict__ hT, const float* __restrict__ Wfc,
                     const float* __restrict__ bfc, float* __restrict__ out) {
    int bb = (blockIdx.x >> 3) << 4;
    int vb = (blockIdx.x & 7) << 4;
    int b  = bb + (threadIdx.x >> 4);
    int v  = vb + (threadIdx.x & 15);
    const uint16_t* hrow = hT + (size_t)b * Hh;
    const float*    wrow = Wfc + (size_t)v * Hh;
    float acc = 0.f;
    #pragma unroll 4
    for (int i = 0; i < Hh; i += 4) {
        float4v wv = *(const float4v*)(wrow + i);
        acc += bf2f(hrow[i + 0]) * wv[0] + bf2f(hrow[i + 1]) * wv[1]
             + bf2f(hrow[i + 2]) * wv[2] + bf2f(hrow[i + 3]) * wv[3];
    }
    out[(size_t)b * Vv + v] = acc + bfc[v];
}

extern "C" void kernel_launch(void* const* d_in, const int* in_sizes, int n_in,
                              void* d_out, int out_size, void* d_ws, size_t ws_size,
                              hipStream_t stream) {
    const int*   x   = (const int*)d_in[0];
    const float* emb = (const float*)d_in[1];
    const float* Wih = (const float*)d_in[2];
    const float* Whh = (const float*)d_in[3];
    const float* bih = (const float*)d_in[4];
    const float* bhh = (const float*)d_in[5];
    const float* Wfc = (const float*)d_in[6];
    const float* bfc = (const float*)d_in[7];
    float* out = (float*)d_out;

    char* ws = (char*)d_ws;
    float*    P     = (float*)ws;                     // 512 KB: [128][1024] f32
    uint16_t* h0    = (uint16_t*)(ws + (512 << 10));  // 256 KB: [128][1024] bf16
    uint16_t* h1    = (uint16_t*)(ws + (768 << 10));  // 256 KB
    uint32_t* flags = (uint32_t*)(ws + (1024 << 10)); // 128 WGs x 16B = 2 KB

    (void)hipMemsetAsync(flags, 0, 4096, stream);     // flags must start at 0 every call
    k_prep<<<512, 256, 0, stream>>>(emb, Wih, bih, bhh, P);
    k_rnn<<<128, 256, 0, stream>>>(x, Whh, P, h0, h1, flags);
    k_fc<<<64, 256, 0, stream>>>(h0, Wfc, bfc, out);
}